// Round 10
// baseline (189.869 us; speedup 1.0000x reference)
//
#include <hip/hip_runtime.h>

#define SEQ 128
#define BATCH 512
#define IN_DIM 128
#define HID 128

typedef float vf2 __attribute__((ext_vector_type(2)));

#define LOG2E 1.4426950408889634f
#define INV2PI 0.15915494309189535f

__device__ __forceinline__ float rcp_f(float x) { return __builtin_amdgcn_rcpf(x); }
// Guaranteed-native transcendentals (single VOP1 each).
__device__ __forceinline__ float exp2_f(float x) { float r; asm("v_exp_f32 %0, %1" : "=v"(r) : "v"(x)); return r; }
__device__ __forceinline__ float sin2pi_f(float x) { float r; asm("v_sin_f32 %0, %1" : "=v"(r) : "v"(x)); return r; }
__device__ __forceinline__ float cos2pi_f(float x) { float r; asm("v_cos_f32 %0, %1" : "=v"(r) : "v"(x)); return r; }
__device__ __forceinline__ float tanh_f(float x) {
  // tanh(x) = 1 - 2/(exp2(x*2log2e)+1)
  return 1.0f - 2.0f * rcp_f(exp2_f(x * 2.885390082f) + 1.0f);
}

template <int CTRL>
__device__ __forceinline__ float dpp_add(float s) {
  return s + __int_as_float(__builtin_amdgcn_mov_dpp(__float_as_int(s), CTRL, 0xF, 0xF, true));
}
__device__ __forceinline__ float rdlane(float v, int src) {
  return __int_as_float(__builtin_amdgcn_readlane(__float_as_int(v), src));
}
__device__ __forceinline__ float bperm_f(int byte_addr, float v) {
  return __int_as_float(__builtin_amdgcn_ds_bpermute(byte_addr, __float_as_int(v)));
}

// ONE WAVE per batch element.  R8 structure (best measured: 90 us dispatch),
// which R9's zero-LDS falsification showed is ~latency-floor-shaped: both LDS
// phases are ~90% schedule-covered; the time is distributed dependent-op
// latency on the arithmetic chain.  R10 trims chain levels / loop overhead:
//  * bias bqv folded into lane c==0's x-partial -> the post-reduce "+bqv"
//    level disappears from the z chain (the row8 allsum distributes it).
//  * 4-step unrolled main loop (halved loop overhead; counted-vmcnt FIFO
//    discipline is invariant: each step issues L(T+2) before consuming L(T+1),
//    so the wait is vmcnt(2) and stores are never drained).
//  * everything else identical to R8: bpermute h-gather (register crossbar),
//    gate exchange via LDS with the xp-tail covering its RAW window,
//    TM recursion / gate GEMM / activation arithmetic bit-identical.
__global__ __launch_bounds__(64) void qlstm_kernel(
    const float* __restrict__ X, const float* __restrict__ Wq, const float* __restrict__ bq,
    const float* __restrict__ pf, const float* __restrict__ pi_, const float* __restrict__ pg,
    const float* __restrict__ po, const float* __restrict__ Wf, const float* __restrict__ bf,
    const float* __restrict__ Wi, const float* __restrict__ bi, const float* __restrict__ Wg,
    const float* __restrict__ bg, const float* __restrict__ Wo, const float* __restrict__ bo,
    float* __restrict__ out)
{
  __shared__ __align__(16) float gsh[4 * HID];   // [gate][128] -- gate exchange only

  const int lane = threadIdx.x;
  const int r = lane >> 3, c = lane & 7;         // dot roles: wire r, dims 16c..16c+15
  const int g = lane >> 4, p = lane & 15;        // gate roles: gate g, act dims 8p..8p+7
  const int b = blockIdx.x;
  const int D0 = 2 * lane;                       // cell-owned dims D0, D0+1

  const float* gW = (g == 0) ? Wf : (g == 1) ? Wi : (g == 2) ? Wg : Wo;
  const float* gB = (g == 0) ? bf : (g == 1) ? bi : (g == 2) ? bg : bo;
  const float* gP = (g == 0) ? pf : (g == 1) ? pi_ : (g == 2) ? pg : po;

  // ---- one-time register preloads (INV2PI folded into wx/wh/bq) ----
  vf2 wx[8], wh[8];
  {
    const vf2* pxw = (const vf2*)(Wq + r * 256 + 16 * c);
    const vf2* phw = (const vf2*)(Wq + r * 256 + 128 + 16 * c);
#pragma unroll
    for (int j = 0; j < 8; ++j) { wx[j] = pxw[j] * INV2PI; wh[j] = phw[j] * INV2PI; }
  }
  // bias enters the reduction through lane c==0's x-partial (off-chain).
  const float bq_add = (c == 0) ? bq[r] * INV2PI : 0.0f;

  const float amul = (g == 2) ? 2.0f : 1.0f;     // tanh = 2*sigmoid(2x)-1
  const float oadd = (g == 2) ? -1.0f : 0.0f;
  const float ksc  = -amul * LOG2E;              // folded: act = exp2(acc)

  vf2 wg2[8][4];
#pragma unroll
  for (int w = 0; w < 8; ++w)
#pragma unroll
    for (int j = 0; j < 4; ++j) {
      wg2[w][j].x = gW[(8 * p + 2 * j)     * 8 + w] * ksc;
      wg2[w][j].y = gW[(8 * p + 2 * j + 1) * 8 + w] * ksc;
    }
  vf2 bias2[4];
#pragma unroll
  for (int j = 0; j < 4; ++j) {
    bias2[j].x = gB[8 * p + 2 * j]     * ksc;
    bias2[j].y = gB[8 * p + 2 * j + 1] * ksc;
  }
  vf2 cbsb[8]; float C1[8], S1[8];
#pragma unroll
  for (int w = 0; w < 8; ++w) {
    float th0 = gP[w], th1 = gP[8 + w];
    cbsb[w].x = cosf(th0); cbsb[w].y = sinf(th0);
    C1[w] = cosf(th1); S1[w] = sinf(th1);
  }

  // bpermute byte-addresses for the h gather: lane (r,c) reads lanes 8c+j
  int bpa[8];
#pragma unroll
  for (int j = 0; j < 8; ++j) bpa[j] = 4 * (8 * c + j);

  // state
  vf2 c2; c2.x = 0.f; c2.y = 0.f;
  vf2 h2v; h2v.x = 0.f; h2v.y = 0.f;
  float hx[8], hy[8];                            // gathered h for the dot (regs)
#pragma unroll
  for (int j = 0; j < 8; ++j) { hx[j] = 0.f; hy[j] = 0.f; }

  const float* xg = X + (size_t)b * IN_DIM + 16 * c;
  float* outp = out + (size_t)b * HID + D0;

  // ---- prologue: xp(t=0) + X(1) into pipeline buffer A ----
  float xp_cur;
  float4 xA0, xA1, xA2, xA3, xB0, xB1, xB2, xB3;
  {
    const float4* x0_ = (const float4*)xg;
    float4 a0 = x0_[0], a1 = x0_[1], a2 = x0_[2], a3 = x0_[3];
    vf2 t0 = wx[0] * (vf2){a0.x, a0.y} + wx[1] * (vf2){a0.z, a0.w};
    vf2 t1 = wx[2] * (vf2){a1.x, a1.y} + wx[3] * (vf2){a1.z, a1.w};
    vf2 t2 = wx[4] * (vf2){a2.x, a2.y} + wx[5] * (vf2){a2.z, a2.w};
    vf2 t3 = wx[6] * (vf2){a3.x, a3.y} + wx[7] * (vf2){a3.z, a3.w};
    vf2 ax = (t0 + t1) + (t2 + t3);
    xp_cur = ax.x + ax.y + bq_add;
    const float4* x1_ = (const float4*)(xg + (size_t)1 * (BATCH * IN_DIM));
    xA0 = x1_[0]; xA1 = x1_[1]; xA2 = x1_[2]; xA3 = x1_[3];
  }

// XC*: buffer holding X(T+1), consumed at this step's xp-tail.
// XL*: buffer to fill with X(TL) where TL = min(T+2, SEQ-1).
#define QSTEP(XC0, XC1, XC2, XC3, XL0, XL1, XL2, XL3, T)                              \
  {                                                                                   \
    /* ---- 0. issue X(T+2) loads: oldest-consumed-first vmem discipline ---- */      \
    {                                                                                 \
      const int tl_ = ((T) + 2 < SEQ) ? (T) + 2 : (SEQ - 1);                          \
      const float4* xn_ = (const float4*)(xg + (size_t)tl_ * (BATCH * IN_DIM));       \
      XL0 = xn_[0]; XL1 = xn_[1]; XL2 = xn_[2]; XL3 = xn_[3];                         \
    }                                                                                 \
    /* ---- 1. chain: q_in dot (tree) + row8 DPP reduce + sincos ---- */              \
    float zz;                                                                         \
    {                                                                                 \
      vf2 t0 = wh[0] * (vf2){hx[0], hy[0]} + wh[1] * (vf2){hx[1], hy[1]};             \
      vf2 t1 = wh[2] * (vf2){hx[2], hy[2]} + wh[3] * (vf2){hx[3], hy[3]};             \
      vf2 t2 = wh[4] * (vf2){hx[4], hy[4]} + wh[5] * (vf2){hx[5], hy[5]};             \
      vf2 t3 = wh[6] * (vf2){hx[6], hy[6]} + wh[7] * (vf2){hx[7], hy[7]};             \
      vf2 aq = ((t0 + t1) + (t2 + t3)) + (vf2){xp_cur, 0.0f};                         \
      float s_ = aq.x + aq.y;                                                         \
      s_ = dpp_add<0xB1>(s_); s_ = dpp_add<0x4E>(s_); s_ = dpp_add<0x141>(s_);        \
      zz = s_;                            /* bias pre-folded; in revolutions */       \
    }                                                                                 \
    float szv = sin2pi_f(zz), czv = cos2pi_f(zz);                                     \
    /* ---- 2. broadcast (c,s) of all 8 wires via readlane -> SGPRs ---- */           \
    float cqs[8], sqs[8];                                                             \
    _Pragma("unroll")                                                                 \
    for (int w = 0; w < 8; ++w) { cqs[w] = rdlane(czv, 8 * w); sqs[w] = rdlane(szv, 8 * w); } \
    /* ---- 3. TM chain + fused gate GEMM (bit-identical to R3) ---- */               \
    vf2 acc0 = bias2[0], acc1 = bias2[1], acc2 = bias2[2], acc3 = bias2[3];           \
    float u_, d_, P_, R_;                                                             \
    {                                                                                 \
      vf2 KA0 = cbsb[0] * cqs[0];                                                     \
      u_ = C1[0]; d_ = C1[0] * KA0.x;                                                 \
      P_ = -S1[0] * KA0.y; R_ = -S1[0] * sqs[0];                                      \
    }                                                                                 \
    _Pragma("unroll")                                                                 \
    for (int w = 1; w < 8; ++w) {                                                     \
      vf2 KA = cbsb[w] * cqs[w];                                                      \
      float K_ = KA.x, A2_ = KA.y, B2_ = sqs[w];                                      \
      float Md = fmaf(A2_, P_, d_);                                                   \
      float MP = fmaf(A2_, d_, P_);                                                   \
      float Mu = fmaf(K_, u_, -(B2_ * R_));                                           \
      float MR = fmaf(B2_, u_, K_ * R_);                                              \
      acc0 += Md * wg2[w - 1][0]; acc1 += Md * wg2[w - 1][1];                         \
      acc2 += Md * wg2[w - 1][2]; acc3 += Md * wg2[w - 1][3];                         \
      u_ = C1[w] * Md; d_ = C1[w] * Mu;                                               \
      P_ = -S1[w] * MP; R_ = -S1[w] * MR;                                             \
    }                                                                                 \
    float ev7_ = d_ + P_;                                                             \
    acc0 += ev7_ * wg2[7][0]; acc1 += ev7_ * wg2[7][1];                               \
    acc2 += ev7_ * wg2[7][2]; acc3 += ev7_ * wg2[7][3];                               \
    /* ---- 4. activation: bare exp2 (scale folded into weights) ---- */              \
    float av_[8] = {acc0.x, acc0.y, acc1.x, acc1.y, acc2.x, acc2.y, acc3.x, acc3.y};  \
    float o8[8];                                                                      \
    _Pragma("unroll")                                                                 \
    for (int k = 0; k < 8; ++k) {                                                     \
      float e_ = exp2_f(av_[k]);                                                      \
      o8[k] = fmaf(rcp_f(1.0f + e_), amul, oadd);                                     \
    }                                                                                 \
    /* ---- 5. gate exchange via LDS; reads issued immediately ---- */                \
    {                                                                                 \
      float4* gp4 = (float4*)(gsh + g * HID + 8 * p);                                 \
      float4 w0; w0.x = o8[0]; w0.y = o8[1]; w0.z = o8[2]; w0.w = o8[3];              \
      float4 w1; w1.x = o8[4]; w1.y = o8[5]; w1.z = o8[6]; w1.w = o8[7];              \
      gp4[0] = w0; gp4[1] = w1;                                                       \
    }                                                                                 \
    vf2 fv = *(const vf2*)(gsh + 0 * HID + D0);                                       \
    vf2 iv = *(const vf2*)(gsh + 1 * HID + D0);                                       \
    vf2 gv = *(const vf2*)(gsh + 2 * HID + D0);                                       \
    vf2 ov = *(const vf2*)(gsh + 3 * HID + D0);                                       \
    /* ---- 6. xp tail from XC (counted vmcnt) -- COVERS the gate RAW trip ---- */    \
    {                                                                                 \
      vf2 t0 = wx[0] * (vf2){XC0.x, XC0.y} + wx[1] * (vf2){XC0.z, XC0.w};             \
      vf2 t1 = wx[2] * (vf2){XC1.x, XC1.y} + wx[3] * (vf2){XC1.z, XC1.w};             \
      vf2 t2 = wx[4] * (vf2){XC2.x, XC2.y} + wx[5] * (vf2){XC2.z, XC2.w};             \
      vf2 t3 = wx[6] * (vf2){XC3.x, XC3.y} + wx[7] * (vf2){XC3.z, XC3.w};             \
      vf2 axn = (t0 + t1) + (t2 + t3);                                                \
      xp_cur = axn.x + axn.y + bq_add;                                                \
    }                                                                                 \
    /* ---- 7. cell update (dims D0, D0+1) ---- */                                    \
    c2 = fv * c2 + iv * gv;                                                           \
    h2v.x = ov.x * tanh_f(c2.x);                                                      \
    h2v.y = ov.y * tanh_f(c2.y);                                                      \
    /* ---- 8. h exchange: 16x ds_bpermute (register crossbar, no RAW) ---- */        \
    _Pragma("unroll")                                                                 \
    for (int j = 0; j < 8; ++j) {                                                     \
      hx[j] = bperm_f(bpa[j], h2v.x);                                                 \
      hy[j] = bperm_f(bpa[j], h2v.y);                                                 \
    }                                                                                 \
    /* ---- 9. output store (covers the bpermute pass) ---- */                        \
    *(vf2*)(outp + (size_t)(T) * (BATCH * HID)) = h2v;                                \
  }

#pragma unroll 1
  for (int tt = 0; tt < SEQ; tt += 4) {
    QSTEP(xA0, xA1, xA2, xA3, xB0, xB1, xB2, xB3, tt);
    QSTEP(xB0, xB1, xB2, xB3, xA0, xA1, xA2, xA3, tt + 1);
    QSTEP(xA0, xA1, xA2, xA3, xB0, xB1, xB2, xB3, tt + 2);
    QSTEP(xB0, xB1, xB2, xB3, xA0, xA1, xA2, xA3, tt + 3);
  }
#undef QSTEP

  // hx, cx
  {
    size_t base = (size_t)SEQ * BATCH * HID;
    *(vf2*)(out + base + (size_t)b * HID + D0) = h2v;
    *(vf2*)(out + base + (size_t)BATCH * HID + (size_t)b * HID + D0) = c2;
  }
}

extern "C" void kernel_launch(void* const* d_in, const int* in_sizes, int n_in,
                              void* d_out, int out_size, void* d_ws, size_t ws_size,
                              hipStream_t stream) {
  (void)in_sizes; (void)n_in; (void)out_size; (void)d_ws; (void)ws_size;
  const float* X   = (const float*)d_in[0];
  const float* Wq  = (const float*)d_in[1];
  const float* bq  = (const float*)d_in[2];
  const float* pf  = (const float*)d_in[3];
  const float* pi_ = (const float*)d_in[4];
  const float* pg  = (const float*)d_in[5];
  const float* po  = (const float*)d_in[6];
  const float* Wf  = (const float*)d_in[7];
  const float* bf  = (const float*)d_in[8];
  const float* Wi  = (const float*)d_in[9];
  const float* bi  = (const float*)d_in[10];
  const float* Wg  = (const float*)d_in[11];
  const float* bg  = (const float*)d_in[12];
  const float* Wo  = (const float*)d_in[13];
  const float* bo  = (const float*)d_in[14];
  float* out = (float*)d_out;

  qlstm_kernel<<<BATCH, 64, 0, stream>>>(X, Wq, bq, pf, pi_, pg, po,
                                         Wf, bf, Wi, bi, Wg, bg, Wo, bo, out);
}